// Round 8
// baseline (1747.836 us; speedup 1.0000x reference)
//
#include <hip/hip_runtime.h>
#include <hip/hip_bf16.h>
#include <math.h>

#define LN_EPS 1e-5f

typedef unsigned short u16;
typedef __attribute__((ext_vector_type(8))) _Float16 f16x8;
typedef __attribute__((ext_vector_type(4))) float f32x4;

__device__ __forceinline__ u16 f2h(float x) {
    _Float16 h = (_Float16)x;
    return __builtin_bit_cast(u16, h);
}
__device__ __forceinline__ void stv(float* p, float v) { *p = v; }
__device__ __forceinline__ void stv(u16* p, float v) { *p = f2h(v); }

__device__ __forceinline__ float gelu_f(float x) {
    const float kA = 0.7978845608028654f;  // sqrt(2/pi)
    return 0.5f * x * (1.f + tanhf(kA * (x + 0.044715f * x * x * x)));
}

// async global->LDS, 16B per lane; LDS dest = wave-uniform base + lane*16
__device__ __forceinline__ void gl_lds16(const u16* g, u16* l) {
    __builtin_amdgcn_global_load_lds(
        (const __attribute__((address_space(1))) unsigned int*)g,
        (__attribute__((address_space(3))) unsigned int*)l, 16, 0, 0);
}
// counted vmem wait (T4): wait until <=N vector-memory ops outstanding
template <int N> __device__ __forceinline__ void s_vmcnt() {
    asm volatile("s_waitcnt vmcnt(%0)" :: "n"(N) : "memory");
}
__device__ __forceinline__ void s_lgkm0() {
    asm volatile("s_waitcnt lgkmcnt(0)" ::: "memory");
    __builtin_amdgcn_sched_barrier(0);
}
__device__ __forceinline__ void bar() { __builtin_amdgcn_s_barrier(); }
__device__ __forceinline__ void sfence() { __builtin_amdgcn_sched_barrier(0); }

// ---------------- LayerNorm: one block per row, templated output ----------------
template <typename OT>
__global__ __launch_bounds__(256) void ln_kernel(const float* __restrict__ x,
                                                 const float* __restrict__ gam,
                                                 const float* __restrict__ bet,
                                                 OT* __restrict__ out) {
    int row = blockIdx.x;
    const float* xr = x + (size_t)row * 1024;
    float v[4];
    float s = 0.f, ss = 0.f;
#pragma unroll
    for (int i = 0; i < 4; i++) {
        float t = xr[threadIdx.x + i * 256];
        v[i] = t; s += t; ss += t * t;
    }
    __shared__ float r1[256], r2[256];
    r1[threadIdx.x] = s; r2[threadIdx.x] = ss;
    __syncthreads();
    for (int off = 128; off > 0; off >>= 1) {
        if (threadIdx.x < off) {
            r1[threadIdx.x] += r1[threadIdx.x + off];
            r2[threadIdx.x] += r2[threadIdx.x + off];
        }
        __syncthreads();
    }
    float mu = r1[0] * (1.f / 1024.f);
    float var = r2[0] * (1.f / 1024.f) - mu * mu;
    float rstd = rsqrtf(var + LN_EPS);
#pragma unroll
    for (int i = 0; i < 4; i++) {
        int c = threadIdx.x + i * 256;
        stv(&out[(size_t)row * 1024 + c], (v[i] - mu) * rstd * gam[c] + bet[c]);
    }
}

// ------- unified weight convert: all 4 weights of one layer in one dispatch -------
__global__ __launch_bounds__(256) void tr_cvt_all(
    const float* __restrict__ Wqkv, const float* __restrict__ Wo,
    const float* __restrict__ Wfc, const float* __restrict__ Wmp,
    u16* __restrict__ wqT, u16* __restrict__ woT,
    u16* __restrict__ wfT, u16* __restrict__ wmT) {
    int id = blockIdx.x;
    const float* W; u16* Wt; int K, N, idx;
    if (id < 768)       { W = Wqkv; Wt = wqT; K = 1024; N = 3072; idx = id; }
    else if (id < 1024) { W = Wo;   Wt = woT; K = 1024; N = 1024; idx = id - 768; }
    else if (id < 2048) { W = Wfc;  Wt = wfT; K = 1024; N = 4096; idx = id - 1024; }
    else                { W = Wmp;  Wt = wmT; K = 4096; N = 1024; idx = id - 2048; }
    int ntn = N >> 6;
    int n0 = (idx % ntn) * 64, k0 = (idx / ntn) * 64;

    __shared__ float tile[64][65];
    int t = threadIdx.x;
    int r = t >> 4, c4 = (t & 15) * 4;
#pragma unroll
    for (int p = 0; p < 4; p++) {
        float4 v = *(const float4*)(W + (size_t)(k0 + p * 16 + r) * N + n0 + c4);
        tile[p * 16 + r][c4 + 0] = v.x;
        tile[p * 16 + r][c4 + 1] = v.y;
        tile[p * 16 + r][c4 + 2] = v.z;
        tile[p * 16 + r][c4 + 3] = v.w;
    }
    __syncthreads();
#pragma unroll
    for (int p = 0; p < 4; p++) {
        int n = p * 16 + r;
        ushort4 o;
        o.x = f2h(tile[c4 + 0][n]);
        o.y = f2h(tile[c4 + 1][n]);
        o.z = f2h(tile[c4 + 2][n]);
        o.w = f2h(tile[c4 + 3][n]);
        *(ushort4*)(Wt + (size_t)(n0 + n) * K + k0 + c4) = o;
    }
}

// ---------------- fp16 MFMA GEMM, 2-phase pipelined, optional split-K ----------------
// out[M,N] = A[M,K] @ Bt[N,K]^T + bias. BMxBN tile, BK k-step, 4 waves (2x2).
// Double-buffered LDS; stage tile t+1 before computing tile t; counted vmcnt.
// k-slot swizzle (slot ^ (row&7)) applied on the GLOBAL source address.
// RES: 0 = plain store; 1 = +res then store; 2 = atomicAdd into out (split-K,
//      bias added by split 0 only). SPLITK: blockIdx.z selects K-chunk.
template <int BM, int BN, int BK, int ACT, int RES, int WVT, int SPLITK, typename OT>
__global__ __launch_bounds__(256, 2) void gemm_f16(
    const u16* __restrict__ A, const u16* __restrict__ Bt,
    const float* __restrict__ bias, const float* __restrict__ res,
    OT* __restrict__ out, u16* __restrict__ vTout, int M, int N, int K) {
    __shared__ u16 As[2][BM * BK];
    __shared__ u16 Bs[2][BN * BK];
    constexpr int WM = BM / 2, WN = BN / 2;
    constexpr int FM = WM / 16, FN = WN / 16;
    constexpr int NKF = BK / 32;
    constexpr int SLOTS = BK / 8;
    constexpr int ACH = BM * BK / 8 / 256;
    constexpr int BCH = BN * BK / 8 / 256;
    constexpr int LPS = ACH + BCH;  // gl_lds16 per thread per stage
    int tid = threadIdx.x;
    int w = tid >> 6, l = tid & 63;
    int wm = w >> 1, wn = w & 1;
    int lr = l & 15, g = l >> 4;
    int m0 = blockIdx.y * BM, n0 = blockIdx.x * BN;
    int kbase = (SPLITK > 1) ? blockIdx.z * (K / SPLITK) : 0;
    int Kc = (SPLITK > 1) ? (K / SPLITK) : K;

    f32x4 acc[FM][FN] = {};

    auto stage = [&](int buf, int k0) {
#pragma unroll
        for (int i = 0; i < ACH; i++) {
            int chunk = i * 256 + tid;
            int row = chunk / SLOTS, s = chunk % SLOTS, sg = s ^ (row & 7);
            gl_lds16(A + (size_t)(m0 + row) * K + kbase + k0 + sg * 8, &As[buf][chunk * 8]);
        }
#pragma unroll
        for (int i = 0; i < BCH; i++) {
            int chunk = i * 256 + tid;
            int row = chunk / SLOTS, s = chunk % SLOTS, sg = s ^ (row & 7);
            gl_lds16(Bt + (size_t)(n0 + row) * K + kbase + k0 + sg * 8, &Bs[buf][chunk * 8]);
        }
    };

    int NT = Kc / BK;
    stage(0, 0);
    int cur = 0;
    for (int t = 0; t < NT; t++) {
        if (t + 1 < NT) { stage(cur ^ 1, (t + 1) * BK); s_vmcnt<LPS>(); }
        else            { s_vmcnt<0>(); }
        bar();      // tile t staged by all waves
        sfence();

        const u16* Ab = &As[cur][0];
        const u16* Bb = &Bs[cur][0];
        f16x8 af[FM][NKF], bfrag[FN][NKF];
#pragma unroll
        for (int m = 0; m < FM; m++)
#pragma unroll
            for (int kf = 0; kf < NKF; kf++) {
                int row = wm * WM + m * 16 + lr;
                af[m][kf] = *(const f16x8*)(Ab + row * BK + (((kf * 4 + g) ^ (row & 7)) * 8));
            }
#pragma unroll
        for (int n = 0; n < FN; n++)
#pragma unroll
            for (int kf = 0; kf < NKF; kf++) {
                int row = wn * WN + n * 16 + lr;
                bfrag[n][kf] = *(const f16x8*)(Bb + row * BK + (((kf * 4 + g) ^ (row & 7)) * 8));
            }
#pragma unroll
        for (int kf = 0; kf < NKF; kf++)
#pragma unroll
            for (int m = 0; m < FM; m++)
#pragma unroll
                for (int n = 0; n < FN; n++)
                    acc[m][n] = __builtin_amdgcn_mfma_f32_16x16x32_f16(
                        af[m][kf], bfrag[n][kf], acc[m][n], 0, 0, 0);

        sfence();
        bar();      // all waves done reading buf[cur] before it is re-staged
        cur ^= 1;
    }

#pragma unroll
    for (int m = 0; m < FM; m++) {
#pragma unroll
        for (int n = 0; n < FN; n++) {
            int col = n0 + wn * WN + n * 16 + lr;
            int row0 = m0 + wm * WM + m * 16 + 4 * g;
            float bv = bias[col];
            u16 hv[4];
#pragma unroll
            for (int r = 0; r < 4; r++) {
                if (RES == 2) {
                    float v = acc[m][n][r] + ((SPLITK > 1 && blockIdx.z != 0) ? 0.f : bv);
                    atomicAdd((float*)&out[(size_t)(row0 + r) * N + col], v);
                } else {
                    float v = acc[m][n][r] + bv;
                    if (ACT) v = gelu_f(v);
                    if (RES == 1) v += res[(size_t)(row0 + r) * N + col];
                    stv(&out[(size_t)(row0 + r) * N + col], v);
                    hv[r] = f2h(v);
                }
            }
            if (WVT && col >= 2048) {
                ushort4 pv; pv.x = hv[0]; pv.y = hv[1]; pv.z = hv[2]; pv.w = hv[3];
                *(ushort4*)(vTout + (size_t)(col - 2048) * 1024 + row0) = pv;
            }
        }
    }
}

// ---------------- flash MFMA attention, KVBLK=128, 2-phase pipelined ----------------
__global__ __launch_bounds__(256) void attn_mfma(
    const u16* __restrict__ qkv, const u16* __restrict__ vT,
    const float* __restrict__ mask, u16* __restrict__ y) {
    int h = blockIdx.y;
    int q0 = blockIdx.x * 64;
    int tid = threadIdx.x;
    int w = tid >> 6, l = tid & 63;
    int lr = l & 15, g = l >> 4;

    __shared__ u16 Ks[2][128 * 64];   // [key][d], 8 slots/row
    __shared__ u16 Vs[2][64 * 128];   // [d][key], 16 slots/row
    __shared__ u16 Ps[4 * 16 * 128];  // per-wave P: [q][key], 16 slots/row
    __shared__ float maskb[1024];

    for (int i = tid; i < 1024; i += 256) maskb[i] = -1e9f * (1.f - mask[i]);
    s_lgkm0();  // own maskb writes landed before first barrier

    f16x8 qf[2];
#pragma unroll
    for (int kf = 0; kf < 2; kf++)
        qf[kf] = *(const f16x8*)(qkv + (size_t)(q0 + w * 16 + lr) * 3072 + h * 64 + kf * 32 + g * 8);

    f32x4 o[4] = {};
    float mrow[4], lrow[4];
#pragma unroll
    for (int r = 0; r < 4; r++) { mrow[r] = -1e30f; lrow[r] = 0.f; }

    u16* Psw = Ps + w * 2048;

    auto stage = [&](int buf, int kc) {
#pragma unroll
        for (int i = 0; i < 4; i++) {
            int chunk = i * 256 + tid;
            int krow = chunk >> 3, ks = chunk & 7, ksg = ks ^ (krow & 7);
            gl_lds16(qkv + (size_t)(kc * 128 + krow) * 3072 + 1024 + h * 64 + ksg * 8,
                     &Ks[buf][chunk * 8]);
            int vrow = chunk >> 4, vs = chunk & 15, vsg = vs ^ (vrow & 7);
            gl_lds16(vT + (size_t)(h * 64 + vrow) * 1024 + kc * 128 + vsg * 8,
                     &Vs[buf][chunk * 8]);
        }
    };

    stage(0, 0);
    int cur = 0;
    for (int kc = 0; kc < 8; kc++) {
        if (kc + 1 < 8) { stage(cur ^ 1, kc + 1); s_vmcnt<8>(); }
        else            { s_vmcnt<0>(); }
        bar();
        sfence();
        const u16* Kb = &Ks[cur][0];
        const u16* Vb = &Vs[cur][0];

        // S = Q @ K^T : 8 key-frags of 16
        f32x4 s[8] = {};
        __builtin_amdgcn_s_setprio(1);
#pragma unroll
        for (int n = 0; n < 8; n++)
#pragma unroll
            for (int kf = 0; kf < 2; kf++) {
                int row = n * 16 + lr;
                f16x8 kfrag = *(const f16x8*)(Kb + row * 64 + (((kf * 4 + g) ^ (row & 7)) * 8));
                s[n] = __builtin_amdgcn_mfma_f32_16x16x32_f16(qf[kf], kfrag, s[n], 0, 0, 0);
            }
        __builtin_amdgcn_s_setprio(0);

        float mcol[8];
#pragma unroll
        for (int n = 0; n < 8; n++) mcol[n] = maskb[kc * 128 + n * 16 + lr];

        float scl[4], mnew[4], psum[4];
#pragma unroll
        for (int r = 0; r < 4; r++) {
            float mx = -1e30f;
#pragma unroll
            for (int n = 0; n < 8; n++) {
                float sv = s[n][r] * 0.125f + mcol[n];
                s[n][r] = sv;
                mx = fmaxf(mx, sv);
            }
            mx = fmaxf(mx, __shfl_xor(mx, 1));
            mx = fmaxf(mx, __shfl_xor(mx, 2));
            mx = fmaxf(mx, __shfl_xor(mx, 4));
            mx = fmaxf(mx, __shfl_xor(mx, 8));
            mnew[r] = fmaxf(mrow[r], mx);
            scl[r] = __expf(mrow[r] - mnew[r]);
            mrow[r] = mnew[r];
            psum[r] = 0.f;
        }
#pragma unroll
        for (int n = 0; n < 8; n++) {
            float p0 = __expf(s[n][0] - mnew[0]);
            float p1 = __expf(s[n][1] - mnew[1]);
            float p2 = __expf(s[n][2] - mnew[2]);
            float p3 = __expf(s[n][3] - mnew[3]);
            psum[0] += p0; psum[1] += p1; psum[2] += p2; psum[3] += p3;
            int col = n * 16 + lr, cs = col >> 3, cl = col & 7;
            int r0 = 4 * g;
            Psw[(r0 + 0) * 128 + ((cs ^ ((r0 + 0) & 7)) * 8) + cl] = f2h(p0);
            Psw[(r0 + 1) * 128 + ((cs ^ ((r0 + 1) & 7)) * 8) + cl] = f2h(p1);
            Psw[(r0 + 2) * 128 + ((cs ^ ((r0 + 2) & 7)) * 8) + cl] = f2h(p2);
            Psw[(r0 + 3) * 128 + ((cs ^ ((r0 + 3) & 7)) * 8) + cl] = f2h(p3);
        }
#pragma unroll
        for (int r = 0; r < 4; r++) {
            float ps_ = psum[r];
            ps_ += __shfl_xor(ps_, 1);
            ps_ += __shfl_xor(ps_, 2);
            ps_ += __shfl_xor(ps_, 4);
            ps_ += __shfl_xor(ps_, 8);
            lrow[r] = lrow[r] * scl[r] + ps_;
#pragma unroll
            for (int dn = 0; dn < 4; dn++) o[dn][r] *= scl[r];
        }

        // PV: A = P (row=q=lr), B = V (row=d). Same-wave LDS RAW is in-order.
        f16x8 pa[4];
#pragma unroll
        for (int kf = 0; kf < 4; kf++)
            pa[kf] = *(const f16x8*)(Psw + lr * 128 + (((kf * 4 + g) ^ (lr & 7)) * 8));
        __builtin_amdgcn_s_setprio(1);
#pragma unroll
        for (int dn = 0; dn < 4; dn++) {
#pragma unroll
            for (int kf = 0; kf < 4; kf++) {
                int row = dn * 16 + lr;
                f16x8 vb = *(const f16x8*)(Vb + row * 128 + (((kf * 4 + g) ^ (row & 7)) * 8));
                o[dn] = __builtin_amdgcn_mfma_f32_16x16x32_f16(pa[kf], vb, o[dn], 0, 0, 0);
            }
        }
        __builtin_amdgcn_s_setprio(0);

        sfence();
        bar();      // all waves done reading buf[cur] before it is re-staged
        cur ^= 1;
    }

    float inv[4];
#pragma unroll
    for (int r = 0; r < 4; r++) inv[r] = 1.f / lrow[r];
#pragma unroll
    for (int dn = 0; dn < 4; dn++)
#pragma unroll
        for (int r = 0; r < 4; r++) {
            int row = q0 + w * 16 + 4 * g + r;
            int col = h * 64 + dn * 16 + lr;
            y[(size_t)row * 1024 + col] = f2h(o[dn][r] * inv[r]);
        }
}

// ---------------- launch ----------------
extern "C" void kernel_launch(void* const* d_in, const int* in_sizes, int n_in,
                              void* d_out, int out_size, void* d_ws, size_t ws_size,
                              hipStream_t stream) {
    const float* inputs_embeds = (const float*)d_in[0];
    const float* attn_mask     = (const float*)d_in[1];
    const float* ln1_g = (const float*)d_in[2];
    const float* ln1_b = (const float*)d_in[3];
    const float* Wqkv  = (const float*)d_in[4];
    const float* bqkv  = (const float*)d_in[5];
    const float* Wo    = (const float*)d_in[6];
    const float* bo    = (const float*)d_in[7];
    const float* ln2_g = (const float*)d_in[8];
    const float* ln2_b = (const float*)d_in[9];
    const float* Wfc   = (const float*)d_in[10];
    const float* bfc   = (const float*)d_in[11];
    const float* Wmp   = (const float*)d_in[12];
    const float* bmp   = (const float*)d_in[13];
    const float* lnf_g = (const float*)d_in[14];
    const float* lnf_b = (const float*)d_in[15];
    float* out = (float*)d_out;

    char* ws = (char*)d_ws;
    float* x   = (float*)ws;                              // 4 MB fp32 residual
    u16* hbuf  = (u16*)(ws + (4u << 20));                 // 2 MB fp16 (ln out / attn y)
    u16* qkvb  = (u16*)(ws + (6u << 20));                 // 8 MB region (qkv 6MB | fc 8MB)
    u16* fcb   = qkvb;
    u16* ybuf  = hbuf;
    u16* wqT   = (u16*)(ws + (14u << 20));                // 6 MB  [3072][1024]
    u16* woT   = (u16*)(ws + (20u << 20));                // 2 MB  [1024][1024]
    u16* wfT   = (u16*)(ws + (22u << 20));                // 8 MB  [4096][1024]
    u16* wmT   = (u16*)(ws + (30u << 20));                // 8 MB  [1024][4096]
    u16* vTb   = (u16*)(ws + (38u << 20));                // 2 MB  [1024][1024] -> 40 MB total

    hipMemcpyAsync(x, inputs_embeds, (size_t)(1 << 20) * sizeof(float),
                   hipMemcpyDeviceToDevice, stream);

    for (int l = 0; l < 12; l++) {
        tr_cvt_all<<<3072, 256, 0, stream>>>(
            Wqkv + (size_t)l * 1024 * 3072, Wo + (size_t)l * 1024 * 1024,
            Wfc + (size_t)l * 1024 * 4096, Wmp + (size_t)l * 4096 * 1024,
            wqT, woT, wfT, wmT);

        ln_kernel<u16><<<1024, 256, 0, stream>>>(x, ln1_g + l * 1024, ln1_b + l * 1024, hbuf);
        // QKV: 1024x3072, 64x128 tiles -> 384 blocks; fused vT write
        gemm_f16<64, 128, 64, 0, 0, 1, 1, u16><<<dim3(24, 16), 256, 0, stream>>>(
            hbuf, wqT, bqkv + (size_t)l * 3072, nullptr, qkvb, vTb, 1024, 3072, 1024);
        attn_mfma<<<dim3(16, 16), 256, 0, stream>>>(qkvb, vTb, attn_mask, ybuf);
        // proj: 1024x1024, 128x128 tiles, splitK=4 (K-chunk 256) -> 256 blocks, atomic res-add
        gemm_f16<128, 128, 64, 0, 2, 0, 4, float><<<dim3(8, 8, 4), 256, 0, stream>>>(
            ybuf, woT, bo + (size_t)l * 1024, nullptr, x, nullptr, 1024, 1024, 1024);
        ln_kernel<u16><<<1024, 256, 0, stream>>>(x, ln2_g + l * 1024, ln2_b + l * 1024, hbuf);
        // FC: 1024x4096, 128x128 tiles -> 256 blocks
        gemm_f16<128, 128, 64, 1, 0, 0, 1, u16><<<dim3(32, 8), 256, 0, stream>>>(
            hbuf, wfT, bfc + (size_t)l * 4096, nullptr, fcb, nullptr, 1024, 4096, 1024);
        // MP: 1024x1024 (K=4096), 128x128 tiles, splitK=8 (K-chunk 512) -> 512 blocks
        gemm_f16<128, 128, 64, 0, 2, 0, 8, float><<<dim3(8, 8, 8), 256, 0, stream>>>(
            fcb, wmT, bmp + (size_t)l * 1024, nullptr, x, nullptr, 1024, 1024, 4096);
    }
    ln_kernel<float><<<1024, 256, 0, stream>>>(x, lnf_g, lnf_b, out);
}